// Round 15
// baseline (521.019 us; speedup 1.0000x reference)
//
#include <hip/hip_runtime.h>
#include <hip/hip_fp16.h>

#define BATCH 16
#define NROW 1024
#define MCOL 1024
#define DFEAT 128

// DP blocking: one wave per batch, 16 rows/thread, 8 cols/phase
#define R_DP 16
#define C_DP 8
#define NCH (MCOL / C_DP)   // 128 chunks along j
#define PSTRIDE 194         // phase slots per batch (incl. prefetch pad)

#define L2E 1.4426950408889634f
#define LN2 0.6931471805599453f

typedef __attribute__((ext_vector_type(8))) short short8;
typedef __attribute__((ext_vector_type(4))) float f32x4;

__device__ inline unsigned short f2bf(float f) {  // RNE f32 -> bf16 bits
  unsigned u = __float_as_uint(f);
  return (unsigned short)((u + 0x7fff + ((u >> 16) & 1)) >> 16);
}

// ---------------------------------------------------------------------------
// Kernel 1: normalize rows and emit bf16 copies. One wave per row.
// ---------------------------------------------------------------------------
__global__ __launch_bounds__(256) void norm_kernel(
    const float* __restrict__ x, const float* __restrict__ y,
    unsigned short* __restrict__ xnb, unsigned short* __restrict__ ynb) {
  int row = blockIdx.x * 4 + (threadIdx.x >> 6);
  int lane = threadIdx.x & 63;
  const float* src;
  unsigned short* dst;
  if (row < BATCH * NROW) {
    src = x + (size_t)row * DFEAT;
    dst = xnb + (size_t)row * DFEAT;
  } else {
    int r2 = row - BATCH * NROW;
    src = y + (size_t)r2 * DFEAT;
    dst = ynb + (size_t)r2 * DFEAT;
  }
  float2 v = *(const float2*)(src + lane * 2);
  float s = v.x * v.x + v.y * v.y;
  #pragma unroll
  for (int o = 32; o > 0; o >>= 1) s += __shfl_xor(s, o, 64);
  float inv = 1.0f / (sqrtf(s) + 1e-8f);
  unsigned short b0 = f2bf(v.x * inv), b1 = f2bf(v.y * inv);
  *(unsigned*)(dst + lane * 2) = (unsigned)b0 | ((unsigned)b1 << 16);
}

// ---------------------------------------------------------------------------
// Kernel 2: MFMA distance GEMM, 128x128 tile/block, phase-major fp16 output
// Dphase[b][p][r][lane][k], p = (j>>3) + (i>>4), r = i&15, k = j&7.
// ---------------------------------------------------------------------------
__global__ __launch_bounds__(256) void dist_kernel(
    const unsigned short* __restrict__ xnb, const unsigned short* __restrict__ ynb,
    __half* __restrict__ Dphase) {
  __shared__ __align__(16) unsigned char xsb[128 * 256];
  __shared__ __align__(16) unsigned char ysb[128 * 256];

  int b = blockIdx.z, ti0 = blockIdx.y, tj0 = blockIdx.x;
  int I0 = ti0 * 128, J0 = tj0 * 128;
  int tid = threadIdx.x;

  const uint4* xsrc = (const uint4*)(xnb + (size_t)(b * NROW + I0) * DFEAT);
  const uint4* ysrc = (const uint4*)(ynb + (size_t)(b * MCOL + J0) * DFEAT);
  #pragma unroll
  for (int it = 0; it < 8; ++it) {
    int idx = tid + it * 256;
    int row = idx >> 4, cb = (idx & 15) * 16;
    int swz = row * 256 + (cb ^ ((row & 7) << 4));
    *(uint4*)&xsb[swz] = xsrc[idx];
    *(uint4*)&ysb[swz] = ysrc[idx];
  }
  __syncthreads();

  int wid = tid >> 6, lane = tid & 63;
  int wi = wid >> 1, wj = wid & 1;
  int lr = lane & 15, lk = lane >> 4;

  f32x4 acc[4][4] = {};
  #pragma unroll
  for (int ks = 0; ks < 4; ++ks) {
    int cb = ks * 64 + lk * 16;
    short8 af[4], bf[4];
    #pragma unroll
    for (int ti = 0; ti < 4; ++ti) {
      int row = wi * 64 + ti * 16 + lr;
      af[ti] = *(short8*)&xsb[row * 256 + (cb ^ ((row & 7) << 4))];
    }
    #pragma unroll
    for (int tj = 0; tj < 4; ++tj) {
      int row = wj * 64 + tj * 16 + lr;
      bf[tj] = *(short8*)&ysb[row * 256 + (cb ^ ((row & 7) << 4))];
    }
    #pragma unroll
    for (int ti = 0; ti < 4; ++ti)
      #pragma unroll
      for (int tj = 0; tj < 4; ++tj)
        acc[ti][tj] = __builtin_amdgcn_mfma_f32_16x16x32_bf16(
            af[ti], bf[tj], acc[ti][tj], 0, 0, 0);
  }

  #pragma unroll
  for (int ti = 0; ti < 4; ++ti) {
    int gi0 = I0 + wi * 64 + ti * 16;
    int l = gi0 >> 4;
    #pragma unroll
    for (int tj = 0; tj < 4; ++tj) {
      int gj = J0 + wj * 64 + tj * 16 + lr;
      int c = gj >> 3, k = gj & 7;
      int p = c + l;
      #pragma unroll
      for (int v = 0; v < 4; ++v) {
        int r = lk * 4 + v;
        float d = 1.0f - acc[ti][tj][v];
        size_t off = ((((size_t)b * PSTRIDE + p) * R_DP + r) * 64 + l) * C_DP + k;
        Dphase[off] = __float2half(exp2f(-d * L2E));
      }
    }
  }
}

// ---------------------------------------------------------------------------
// Kernel 3: exp-domain soft-DTW DP (r13 structure). r15 change: EXEC-MASKED
// loads during ramp phases — lanes whose next-phase chunk is out of range
// issue no memory traffic (kills the 1.55x skew-padding fetch waste).
// Plus two ABLATION kernels (dtw_nold / dtw_nocmp) dispatched to scratch to
// split phase time into compute vs delivery (r11-r14: 4 null/negative
// results -> measure before optimizing further).
// ---------------------------------------------------------------------------
__device__ __forceinline__ float shup(float x, bool edge) {
  int xi = __float_as_int(x);
  int sh = __builtin_amdgcn_update_dpp(xi, xi, 0x111, 0xF, 0xF, false); // row_shr:1
  int bc = __builtin_amdgcn_update_dpp(xi, xi, 0x142, 0xF, 0xF, false); // row_bcast15
  return __int_as_float(edge ? bc : sh);
}

// A = f16(lo/hi of h) * s      (fzero VGPR)
#define MIXMUL_LO(A, h, s) \
  asm("v_fma_mix_f32 %0, %1, %2, %3 op_sel_hi:[1,0,0]" : "=v"(A) : "v"(h), "v"(s), "v"(fzero))
#define MIXMUL_HI(A, h, s) \
  asm("v_fma_mix_f32 %0, %1, %2, %3 op_sel:[1,0,0] op_sel_hi:[1,0,0]" : "=v"(A) : "v"(h), "v"(s), "v"(fzero))
// lf = f16(lo/hi of h) * lf + a
#define MIXFMA_LO(lf, h, a) \
  asm("v_fma_mix_f32 %0, %1, %2, %3 op_sel_hi:[1,0,0]" : "=v"(lf) : "v"(h), "v"(lf), "v"(a))
#define MIXFMA_HI(lf, h, a) \
  asm("v_fma_mix_f32 %0, %1, %2, %3 op_sel:[1,0,0] op_sel_hi:[1,0,0]" : "=v"(lf) : "v"(h), "v"(lf), "v"(a))

template<bool GUARDED>
__device__ __forceinline__ void dtw_phase(int c, int t, bool edge,
    const uint4* L, float* carry, float (&B)[9], float& O, float fzero) {
  float U[9];
  #pragma unroll
  for (int k = 0; k < 9; ++k) U[k] = shup(B[k], edge);
  float Oin = shup(O, edge);
  if (t == 0) {
    #pragma unroll
    for (int k = 0; k < 9; ++k) U[k] = 0.0f;
    if (GUARDED && c == 0) U[0] = 1.0f;   // E[0][0] = exp(-0)
    Oin = O;
  }
  bool act = GUARDED ? (c >= 0 && c < NCH) : true;
  if (act) {
    if (GUARDED && c == 0) O = Oin;       // adopt neighbor's frame
    float sc = exp2f((O - Oin) * L2E);
    #pragma unroll
    for (int k = 0; k < 9; ++k) U[k] *= sc;

    #pragma unroll
    for (int r = 0; r < R_DP; ++r) {
      uint4 d = L[r];
      unsigned dw[4] = {d.x, d.y, d.z, d.w};
      float S[8], A[8];
      #pragma unroll
      for (int k = 0; k < 8; ++k) S[k] = U[k] + U[k + 1];
      #pragma unroll
      for (int q = 0; q < 4; ++q) {
        MIXMUL_LO(A[2 * q],     dw[q], S[2 * q]);
        MIXMUL_HI(A[2 * q + 1], dw[q], S[2 * q + 1]);
      }
      float oldc = carry[r], lf = oldc;
      float V[8];
      #pragma unroll
      for (int q = 0; q < 4; ++q) {
        MIXFMA_LO(lf, dw[q], A[2 * q]);     V[2 * q] = lf;
        MIXFMA_HI(lf, dw[q], A[2 * q + 1]); V[2 * q + 1] = lf;
      }
      U[0] = oldc;
      #pragma unroll
      for (int k = 1; k <= 8; ++k) U[k] = V[k - 1];
      carry[r] = lf;
    }

    // renorm: E *= 2^-ex  =>  O -= ex*ln2 ; window [-20,+12]
    float rep = carry[R_DP - 1];
    int ex = (int)((__float_as_uint(rep) >> 23) & 0xFF) - 127;
    if ((ex < -20 || ex > 12) && ex < 128) {
      float s = __uint_as_float((unsigned)(127 - ex) << 23);  // 2^-ex
      #pragma unroll
      for (int r = 0; r < R_DP; ++r) carry[r] *= s;
      #pragma unroll
      for (int k = 0; k < 9; ++k) U[k] *= s;
      O -= (float)ex * LN2;
    }
    #pragma unroll
    for (int k = 0; k < 9; ++k) B[k] = U[k];
  }
}

#define GL(Lr, SB, OFF) \
  asm volatile("global_load_dwordx4 %0, %1, %2 offset:" OFF : "=v"(Lr) : "v"(voff), "s"(SB));

#define ISSUE16(L)                                               \
  GL(L[0],  s0, "0")    GL(L[1],  s0, "1024")                    \
  GL(L[2],  s0, "2048") GL(L[3],  s0, "3072")                    \
  GL(L[4],  s1, "0")    GL(L[5],  s1, "1024")                    \
  GL(L[6],  s1, "2048") GL(L[7],  s1, "3072")                    \
  GL(L[8],  s2, "0")    GL(L[9],  s2, "1024")                    \
  GL(L[10], s2, "2048") GL(L[11], s2, "3072")                    \
  GL(L[12], s3, "0")    GL(L[13], s3, "1024")                    \
  GL(L[14], s3, "2048") GL(L[15], s3, "3072")

#define ADV() { s0 += 16384; s1 += 16384; s2 += 16384; s3 += 16384; }

#define WAITC()                                       \
  asm volatile("s_waitcnt vmcnt(16)" ::: "memory");   \
  __builtin_amdgcn_sched_barrier(0);

#define SETUP_BASES()                                                        \
  const char* g = (const char*)Dphase + (size_t)b * PSTRIDE * 16384;         \
  const char* s0 = g;                                                        \
  const char* s1 = g + 4096;                                                 \
  const char* s2 = g + 8192;                                                 \
  const char* s3 = g + 12288;

// masked issue: lanes whose phase-(PP) chunk is out of range fetch nothing
#define STEP2M(PP, G, MASKED)                                                \
  ADV();                                                                     \
  if (!(MASKED) || (unsigned)((PP) + 1 - t) < 128u) { ISSUE16(LB) }          \
  WAITC();                                                                   \
  dtw_phase<G>((PP) - t, t, edge, LA, carry, B, O, fzero);                   \
  ADV();                                                                     \
  if (!(MASKED) || (unsigned)((PP) + 2 - t) < 128u) { ISSUE16(LA) }          \
  WAITC();                                                                   \
  dtw_phase<G>((PP) + 1 - t, t, edge, LB, carry, B, O, fzero);

__global__ __launch_bounds__(64, 1) void dtw_kernel(
    const __half* __restrict__ Dphase, float* __restrict__ out) {
  int b = blockIdx.x;
  int t = threadIdx.x;
  const bool edge = (t != 0) && ((t & 15) == 0);
  float fzero = 0.0f;
  int voff = t * 16;

  SETUP_BASES();

  float carry[R_DP];
  #pragma unroll
  for (int r = 0; r < R_DP; ++r) carry[r] = 0.0f;
  float B[9] = {};
  float O = 0.0f;

  uint4 LA[R_DP], LB[R_DP];
  if (t == 0) { ISSUE16(LA) }            // phase 0: only lane 0 consumes

  for (int p = 0; p < 64; p += 2)   { STEP2M(p, true, true) }
  for (int p = 64; p < 128; p += 2) { STEP2M(p, false, false) }
  for (int p = 128; p < 192; p += 2){ STEP2M(p, true, true) }

  asm volatile("s_waitcnt vmcnt(0)" ::: "memory");

  if (t == 63) out[b] = O - logf(carry[R_DP - 1]);  // R[N][M]
}

// --- ABLATION A: no loads, full compute on static registers ----------------
__global__ __launch_bounds__(64, 1) void dtw_nold(
    const __half* __restrict__ Dphase, float* __restrict__ scr) {
  int b = blockIdx.x;
  int t = threadIdx.x;
  const bool edge = (t != 0) && ((t & 15) == 0);
  float fzero = 0.0f;
  int voff = t * 16;

  SETUP_BASES();

  float carry[R_DP];
  #pragma unroll
  for (int r = 0; r < R_DP; ++r) carry[r] = 0.0f;
  float B[9] = {};
  float O = 0.0f;

  uint4 LA[R_DP];
  ISSUE16(LA);
  asm volatile("s_waitcnt vmcnt(0)" ::: "memory");
  (void)s0; (void)s1; (void)s2; (void)s3;

  for (int p = 0; p < 64; p += 2) {
    dtw_phase<true>(p - t, t, edge, LA, carry, B, O, fzero);
    dtw_phase<true>(p + 1 - t, t, edge, LA, carry, B, O, fzero);
  }
  for (int p = 64; p < 128; p += 2) {
    dtw_phase<false>(p - t, t, edge, LA, carry, B, O, fzero);
    dtw_phase<false>(p + 1 - t, t, edge, LA, carry, B, O, fzero);
  }
  for (int p = 128; p < 192; p += 2) {
    dtw_phase<true>(p - t, t, edge, LA, carry, B, O, fzero);
    dtw_phase<true>(p + 1 - t, t, edge, LA, carry, B, O, fzero);
  }
  scr[b * 64 + t] = O + carry[R_DP - 1] + B[0];   // keep everything live
}

// --- ABLATION B: full loads + waits, compute replaced by xor-sink ----------
__global__ __launch_bounds__(64, 1) void dtw_nocmp(
    const __half* __restrict__ Dphase, unsigned* __restrict__ scr) {
  int b = blockIdx.x;
  int t = threadIdx.x;
  int voff = t * 16;

  SETUP_BASES();

  uint4 LA[R_DP], LB[R_DP];
  ISSUE16(LA);
  unsigned acc = 0;
  for (int p = 0; p < 192; p += 2) {
    ADV(); ISSUE16(LB) WAITC();
    #pragma unroll
    for (int r = 0; r < R_DP; ++r) acc ^= LA[r].x ^ LA[r].y ^ LA[r].z ^ LA[r].w;
    ADV(); ISSUE16(LA) WAITC();
    #pragma unroll
    for (int r = 0; r < R_DP; ++r) acc ^= LB[r].x ^ LB[r].y ^ LB[r].z ^ LB[r].w;
  }
  asm volatile("s_waitcnt vmcnt(0)" ::: "memory");
  scr[b * 64 + t] = acc;                          // keep loads live
}

// ---------------------------------------------------------------------------
extern "C" void kernel_launch(void* const* d_in, const int* in_sizes, int n_in,
                              void* d_out, int out_size, void* d_ws, size_t ws_size,
                              hipStream_t stream) {
  const float* x = (const float*)d_in[0];
  const float* y = (const float*)d_in[1];
  float* out = (float*)d_out;

  char* ws = (char*)d_ws;
  __half* Dphase = (__half*)ws;
  size_t dp_bytes = (size_t)BATCH * PSTRIDE * 16384;   // ~50.9 MB
  unsigned short* xnb = (unsigned short*)(ws + dp_bytes);          // 4 MB
  unsigned short* ynb = xnb + (size_t)BATCH * NROW * DFEAT;        // 4 MB
  float* scrA = (float*)(ynb + (size_t)BATCH * NROW * DFEAT);      // 4 KB
  unsigned* scrB = (unsigned*)(scrA + BATCH * 64);                 // 4 KB

  norm_kernel<<<(2 * BATCH * NROW) / 4, 256, 0, stream>>>(x, y, xnb, ynb);
  dist_kernel<<<dim3(MCOL / 128, NROW / 128, BATCH), 256, 0, stream>>>(
      xnb, ynb, Dphase);
  dtw_kernel<<<BATCH, 64, 0, stream>>>(Dphase, out);
  // diagnostics (scratch-only; remove next round)
  dtw_nold<<<BATCH, 64, 0, stream>>>(Dphase, scrA);
  dtw_nocmp<<<BATCH, 64, 0, stream>>>(Dphase, scrB);
}

// Round 16
// 292.505 us; speedup vs baseline: 1.7812x; 1.7812x over previous
//
#include <hip/hip_runtime.h>
#include <hip/hip_fp16.h>

#define BATCH 16
#define NROW 1024
#define MCOL 1024
#define DFEAT 128

// DP blocking: 4 waves per batch (1/SIMD), 4 rows/lane, 8 cols/phase
#define R_DP 4
#define C_DP 8
#define NCH (MCOL / C_DP)     // 128 chunks along j
#define NPHT 384              // executed phases (191 per wave window, skewed)
#define BATCH_BYTES 2097152   // parallelogram-compact: exactly 2 MB/batch

#define L2E 1.4426950408889634f
#define LN2 0.6931471805599453f

typedef __attribute__((ext_vector_type(8))) short short8;
typedef __attribute__((ext_vector_type(4))) float f32x4;

__device__ inline unsigned short f2bf(float f) {  // RNE f32 -> bf16 bits
  unsigned u = __float_as_uint(f);
  return (unsigned short)((u + 0x7fff + ((u >> 16) & 1)) >> 16);
}

// byte offset of phase-P region within a batch (parallelogram prefix sum)
// width(P) = min(P,255) - max(0,P-127) + 1 slots of 64 B
__device__ __forceinline__ int pbase(int P) {
  return (P < 128) ? 32 * P * (P + 1)
       : (P < 256) ? 528384 + ((P - 128) << 13)
                   : 1576960 + 32 * (16256 - (383 - P) * (384 - P));
}

// ---------------------------------------------------------------------------
// Kernel 1: normalize rows and emit bf16 copies. One wave per row.
// ---------------------------------------------------------------------------
__global__ __launch_bounds__(256) void norm_kernel(
    const float* __restrict__ x, const float* __restrict__ y,
    unsigned short* __restrict__ xnb, unsigned short* __restrict__ ynb) {
  int row = blockIdx.x * 4 + (threadIdx.x >> 6);
  int lane = threadIdx.x & 63;
  const float* src;
  unsigned short* dst;
  if (row < BATCH * NROW) {
    src = x + (size_t)row * DFEAT;
    dst = xnb + (size_t)row * DFEAT;
  } else {
    int r2 = row - BATCH * NROW;
    src = y + (size_t)r2 * DFEAT;
    dst = ynb + (size_t)r2 * DFEAT;
  }
  float2 v = *(const float2*)(src + lane * 2);
  float s = v.x * v.x + v.y * v.y;
  #pragma unroll
  for (int o = 32; o > 0; o >>= 1) s += __shfl_xor(s, o, 64);
  float inv = 1.0f / (sqrtf(s) + 1e-8f);
  unsigned short b0 = f2bf(v.x * inv), b1 = f2bf(v.y * inv);
  *(unsigned*)(dst + lane * 2) = (unsigned)b0 | ((unsigned)b1 << 16);
}

// ---------------------------------------------------------------------------
// Kernel 2: MFMA distance GEMM. Epilogue stores exp(-(1-dot)) fp16 in the
// parallelogram-compact layout: cell (i,j) -> gl = i>>2, c = j>>3, P = c+gl,
// slot addr = pbase(P) + (gl - max(0,P-127))*64 + (i&3)*16 + (j&7)*2.
// ---------------------------------------------------------------------------
__global__ __launch_bounds__(256) void dist_kernel(
    const unsigned short* __restrict__ xnb, const unsigned short* __restrict__ ynb,
    char* __restrict__ Dpar) {
  __shared__ __align__(16) unsigned char xsb[128 * 256];
  __shared__ __align__(16) unsigned char ysb[128 * 256];

  int b = blockIdx.z, ti0 = blockIdx.y, tj0 = blockIdx.x;
  int I0 = ti0 * 128, J0 = tj0 * 128;
  int tid = threadIdx.x;

  const uint4* xsrc = (const uint4*)(xnb + (size_t)(b * NROW + I0) * DFEAT);
  const uint4* ysrc = (const uint4*)(ynb + (size_t)(b * MCOL + J0) * DFEAT);
  #pragma unroll
  for (int it = 0; it < 8; ++it) {
    int idx = tid + it * 256;
    int row = idx >> 4, cb = (idx & 15) * 16;
    int swz = row * 256 + (cb ^ ((row & 7) << 4));
    *(uint4*)&xsb[swz] = xsrc[idx];
    *(uint4*)&ysb[swz] = ysrc[idx];
  }
  __syncthreads();

  int wid = tid >> 6, lane = tid & 63;
  int wi = wid >> 1, wj = wid & 1;
  int lr = lane & 15, lk = lane >> 4;

  f32x4 acc[4][4] = {};
  #pragma unroll
  for (int ks = 0; ks < 4; ++ks) {
    int cb = ks * 64 + lk * 16;
    short8 af[4], bf[4];
    #pragma unroll
    for (int ti = 0; ti < 4; ++ti) {
      int row = wi * 64 + ti * 16 + lr;
      af[ti] = *(short8*)&xsb[row * 256 + (cb ^ ((row & 7) << 4))];
    }
    #pragma unroll
    for (int tj = 0; tj < 4; ++tj) {
      int row = wj * 64 + tj * 16 + lr;
      bf[tj] = *(short8*)&ysb[row * 256 + (cb ^ ((row & 7) << 4))];
    }
    #pragma unroll
    for (int ti = 0; ti < 4; ++ti)
      #pragma unroll
      for (int tj = 0; tj < 4; ++tj)
        acc[ti][tj] = __builtin_amdgcn_mfma_f32_16x16x32_bf16(
            af[ti], bf[tj], acc[ti][tj], 0, 0, 0);
  }

  char* Db = Dpar + (size_t)b * BATCH_BYTES;
  #pragma unroll
  for (int ti = 0; ti < 4; ++ti) {
    int gi0 = I0 + wi * 64 + ti * 16 + lk * 4;  // 4-aligned; v = row-in-slot
    int gl = gi0 >> 2;
    #pragma unroll
    for (int tj = 0; tj < 4; ++tj) {
      int gj = J0 + wj * 64 + tj * 16 + lr;
      int c = gj >> 3, k = gj & 7;
      int P = c + gl;
      int gmn = P > 127 ? P - 127 : 0;
      char* slot = Db + pbase(P) + ((gl - gmn) << 6) + (k << 1);
      #pragma unroll
      for (int v = 0; v < 4; ++v) {
        float d = 1.0f - acc[ti][tj][v];
        *(__half*)(slot + v * 16) = __float2half(exp2f(-d * L2E));
      }
    }
  }
}

// ---------------------------------------------------------------------------
// Kernel 3: exp-domain soft-DTW DP, 4 waves/batch (one per SIMD).
// Wave w lane t owns rows 4*(64w+t)..+3; phase P handles chunk c = P-64w-t.
// Intra-wave handoff: DPP (r13). Wave-seam: LDS bnd[parity][w][10] (r5
// scheme). Raw s_barrier + lgkm-only drain (register loads stay in flight);
// counted vmcnt(4); wave-uniform execz skip outside [64w, 64w+190].
// Math identical to the r5/r13-verified recurrence (E = exp(O-R); renorm
// E *= 2^-ex => O -= ex*ln2).
// ---------------------------------------------------------------------------

// A = f16(lo/hi of h) * s      (fzero VGPR)
#define MIXMUL_LO(A, h, s) \
  asm("v_fma_mix_f32 %0, %1, %2, %3 op_sel_hi:[1,0,0]" : "=v"(A) : "v"(h), "v"(s), "v"(fzero))
#define MIXMUL_HI(A, h, s) \
  asm("v_fma_mix_f32 %0, %1, %2, %3 op_sel:[1,0,0] op_sel_hi:[1,0,0]" : "=v"(A) : "v"(h), "v"(s), "v"(fzero))
// lf = f16(lo/hi of h) * lf + a
#define MIXFMA_LO(lf, h, a) \
  asm("v_fma_mix_f32 %0, %1, %2, %3 op_sel_hi:[1,0,0]" : "=v"(lf) : "v"(h), "v"(lf), "v"(a))
#define MIXFMA_HI(lf, h, a) \
  asm("v_fma_mix_f32 %0, %1, %2, %3 op_sel:[1,0,0] op_sel_hi:[1,0,0]" : "=v"(lf) : "v"(h), "v"(lf), "v"(a))

__device__ __forceinline__ float shup(float x, bool edge) {
  int xi = __float_as_int(x);
  int sh = __builtin_amdgcn_update_dpp(xi, xi, 0x111, 0xF, 0xF, false); // row_shr:1
  int bc = __builtin_amdgcn_update_dpp(xi, xi, 0x142, 0xF, 0xF, false); // row_bcast15
  return __int_as_float(edge ? bc : sh);
}

__device__ __forceinline__ void dtw_phase4(int cbase, int t, int w, bool edge,
    const uint4* L, float* carry, float (&B)[9], float& O, float fzero,
    const float* bndPrev) {
  int c = cbase - t;
  float U[9];
  #pragma unroll
  for (int k = 0; k < 9; ++k) U[k] = shup(B[k], edge);
  float Oin = shup(O, edge);
  if (t == 0) {
    if (w == 0) {
      #pragma unroll
      for (int k = 0; k < 9; ++k) U[k] = 0.0f;
      U[0] = (c == 0) ? 1.0f : 0.0f;    // E[0][0] = exp(-0)
      Oin = O;
    } else {
      #pragma unroll
      for (int k = 0; k < 9; ++k) U[k] = bndPrev[k];
      Oin = bndPrev[9];
    }
  }
  if ((unsigned)c < 128u) {
    if (c == 0) O = Oin;                // adopt neighbor's frame at activation
    float sc = exp2f((O - Oin) * L2E);
    #pragma unroll
    for (int k = 0; k < 9; ++k) U[k] *= sc;

    #pragma unroll
    for (int r = 0; r < R_DP; ++r) {
      uint4 d = L[r];
      unsigned dw[4] = {d.x, d.y, d.z, d.w};
      float S[8], A[8];
      #pragma unroll
      for (int k = 0; k < 8; ++k) S[k] = U[k] + U[k + 1];
      #pragma unroll
      for (int q = 0; q < 4; ++q) {
        MIXMUL_LO(A[2 * q],     dw[q], S[2 * q]);
        MIXMUL_HI(A[2 * q + 1], dw[q], S[2 * q + 1]);
      }
      float oldc = carry[r], lf = oldc;
      float V[8];
      #pragma unroll
      for (int q = 0; q < 4; ++q) {
        MIXFMA_LO(lf, dw[q], A[2 * q]);     V[2 * q] = lf;
        MIXFMA_HI(lf, dw[q], A[2 * q + 1]); V[2 * q + 1] = lf;
      }
      U[0] = oldc;
      #pragma unroll
      for (int k = 1; k <= 8; ++k) U[k] = V[k - 1];
      carry[r] = lf;
    }

    // renorm: E *= 2^-ex  =>  O -= ex*ln2 ; window [-20,+12]
    float rep = carry[R_DP - 1];
    int ex = (int)((__float_as_uint(rep) >> 23) & 0xFF) - 127;
    if ((ex < -20 || ex > 12) && ex < 128) {
      float s = __uint_as_float((unsigned)(127 - ex) << 23);  // 2^-ex
      #pragma unroll
      for (int r = 0; r < R_DP; ++r) carry[r] *= s;
      #pragma unroll
      for (int k = 0; k < 9; ++k) U[k] *= s;
      O -= (float)ex * LN2;
    }
    #pragma unroll
    for (int k = 0; k < 9; ++k) B[k] = U[k];
  }
}

#define GL4(Lr, SB, OFF) \
  asm volatile("global_load_dwordx4 %0, %1, %2 offset:" OFF : "=v"(Lr) : "v"(voff), "s"(SB));
#define ISSUE4(L, SB) \
  GL4(L[0], SB, "0") GL4(L[1], SB, "16") GL4(L[2], SB, "32") GL4(L[3], SB, "48")

#define STEP(P, CUR, NXT)                                                    \
  {                                                                          \
    int Pn = (P) + 1;                                                        \
    int gmn = Pn > 127 ? Pn - 127 : 0;                                       \
    const char* sb = gb + (pbase(Pn) + ((w64 - gmn) << 6));                  \
    ISSUE4(NXT, sb)                                                          \
    asm volatile("s_waitcnt vmcnt(4)" ::: "memory");                         \
    __builtin_amdgcn_sched_barrier(0);                                       \
    if ((unsigned)((P) - w64) < 191u) {                                      \
      dtw_phase4((P) - w64, t, w, edge, CUR, carry, B, O, fzero,             \
                 &bnd[(P) & 1][w > 0 ? w - 1 : 0][0]);                       \
      if (t == 63) {                                                         \
        float* bn = &bnd[((P) + 1) & 1][w][0];                               \
        _Pragma("unroll")                                                    \
        for (int k = 0; k < 9; ++k) bn[k] = B[k];                            \
        bn[9] = O;                                                           \
      }                                                                      \
    }                                                                        \
    asm volatile("s_waitcnt lgkmcnt(0)" ::: "memory");                       \
    __builtin_amdgcn_s_barrier();                                            \
    asm volatile("" ::: "memory");                                           \
  }

__global__ __launch_bounds__(256, 1) void dtw_kernel(
    const char* __restrict__ Dpar, float* __restrict__ out) {
  int b = blockIdx.x;
  int tid = threadIdx.x;
  int w = __builtin_amdgcn_readfirstlane(tid >> 6);   // wave id (SGPR)
  int t = tid & 63;
  int w64 = w << 6;
  const bool edge = (t != 0) && ((t & 15) == 0);
  float fzero = 0.0f;
  int voff = t << 6;                    // lane slot = 64 B

  __shared__ float bnd[2][4][10];
  if (tid < 80) ((float*)bnd)[tid] = 0.0f;
  __syncthreads();

  const char* gb = Dpar + (size_t)b * BATCH_BYTES;

  float carry[R_DP] = {0.f, 0.f, 0.f, 0.f};
  float B[9] = {};
  float O = 0.0f;

  uint4 LA[R_DP], LB[R_DP];
  {
    const char* sb = gb + (w64 << 6);   // pbase(0)=0, glmin=0
    ISSUE4(LA, sb)
  }

  for (int p = 0; p < NPHT; p += 2) {
    STEP(p, LA, LB)
    STEP(p + 1, LB, LA)
  }

  asm volatile("s_waitcnt vmcnt(0)" ::: "memory");

  if (tid == 255) out[b] = O - logf(carry[R_DP - 1]);  // R[N][M]
}

// ---------------------------------------------------------------------------
extern "C" void kernel_launch(void* const* d_in, const int* in_sizes, int n_in,
                              void* d_out, int out_size, void* d_ws, size_t ws_size,
                              hipStream_t stream) {
  const float* x = (const float*)d_in[0];
  const float* y = (const float*)d_in[1];
  float* out = (float*)d_out;

  char* ws = (char*)d_ws;
  char* Dpar = ws;                                          // 32 MB compact
  size_t dp_bytes = (size_t)BATCH * BATCH_BYTES;
  unsigned short* xnb = (unsigned short*)(ws + dp_bytes);   // 4 MB
  unsigned short* ynb = xnb + (size_t)BATCH * NROW * DFEAT; // 4 MB

  norm_kernel<<<(2 * BATCH * NROW) / 4, 256, 0, stream>>>(x, y, xnb, ynb);
  dist_kernel<<<dim3(MCOL / 128, NROW / 128, BATCH), 256, 0, stream>>>(
      xnb, ynb, Dpar);
  dtw_kernel<<<BATCH, 256, 0, stream>>>(Dpar, out);
}

// Round 17
// 286.175 us; speedup vs baseline: 1.8206x; 1.0221x over previous
//
#include <hip/hip_runtime.h>
#include <hip/hip_fp16.h>

#define BATCH 16
#define NROW 1024
#define MCOL 1024
#define DFEAT 128

// DP blocking: consumer wave owns a batch; lane t rows 16t..16t+15; 8 cols/phase
#define R_DP 16
#define C_DP 8
#define NCH (MCOL / C_DP)   // 128 chunks along j
#define NPH_C 191           // consumer phases 0..190 (last active = 190)
#define PSTRIDE 194         // phase slots per batch in Dphase

#define L2E 1.4426950408889634f
#define LN2 0.6931471805599453f

typedef __attribute__((ext_vector_type(8))) short short8;
typedef __attribute__((ext_vector_type(4))) float f32x4;

__device__ inline unsigned short f2bf(float f) {  // RNE f32 -> bf16 bits
  unsigned u = __float_as_uint(f);
  return (unsigned short)((u + 0x7fff + ((u >> 16) & 1)) >> 16);
}

// ---------------------------------------------------------------------------
// Kernel 1: normalize rows and emit bf16 copies. One wave per row.
// ---------------------------------------------------------------------------
__global__ __launch_bounds__(256) void norm_kernel(
    const float* __restrict__ x, const float* __restrict__ y,
    unsigned short* __restrict__ xnb, unsigned short* __restrict__ ynb) {
  int row = blockIdx.x * 4 + (threadIdx.x >> 6);
  int lane = threadIdx.x & 63;
  const float* src;
  unsigned short* dst;
  if (row < BATCH * NROW) {
    src = x + (size_t)row * DFEAT;
    dst = xnb + (size_t)row * DFEAT;
  } else {
    int r2 = row - BATCH * NROW;
    src = y + (size_t)r2 * DFEAT;
    dst = ynb + (size_t)r2 * DFEAT;
  }
  float2 v = *(const float2*)(src + lane * 2);
  float s = v.x * v.x + v.y * v.y;
  #pragma unroll
  for (int o = 32; o > 0; o >>= 1) s += __shfl_xor(s, o, 64);
  float inv = 1.0f / (sqrtf(s) + 1e-8f);
  unsigned short b0 = f2bf(v.x * inv), b1 = f2bf(v.y * inv);
  *(unsigned*)(dst + lane * 2) = (unsigned)b0 | ((unsigned)b1 << 16);
}

// ---------------------------------------------------------------------------
// Kernel 2: MFMA distance GEMM, phase-major fp16 output (r13 layout):
// Dphase[b][p][r][lane][k], p = (j>>3) + (i>>4), r = i&15, k = j&7.
// ---------------------------------------------------------------------------
__global__ __launch_bounds__(256) void dist_kernel(
    const unsigned short* __restrict__ xnb, const unsigned short* __restrict__ ynb,
    __half* __restrict__ Dphase) {
  __shared__ __align__(16) unsigned char xsb[128 * 256];
  __shared__ __align__(16) unsigned char ysb[128 * 256];

  int b = blockIdx.z, ti0 = blockIdx.y, tj0 = blockIdx.x;
  int I0 = ti0 * 128, J0 = tj0 * 128;
  int tid = threadIdx.x;

  const uint4* xsrc = (const uint4*)(xnb + (size_t)(b * NROW + I0) * DFEAT);
  const uint4* ysrc = (const uint4*)(ynb + (size_t)(b * MCOL + J0) * DFEAT);
  #pragma unroll
  for (int it = 0; it < 8; ++it) {
    int idx = tid + it * 256;
    int row = idx >> 4, cb = (idx & 15) * 16;
    int swz = row * 256 + (cb ^ ((row & 7) << 4));
    *(uint4*)&xsb[swz] = xsrc[idx];
    *(uint4*)&ysb[swz] = ysrc[idx];
  }
  __syncthreads();

  int wid = tid >> 6, lane = tid & 63;
  int wi = wid >> 1, wj = wid & 1;
  int lr = lane & 15, lk = lane >> 4;

  f32x4 acc[4][4] = {};
  #pragma unroll
  for (int ks = 0; ks < 4; ++ks) {
    int cb = ks * 64 + lk * 16;
    short8 af[4], bf[4];
    #pragma unroll
    for (int ti = 0; ti < 4; ++ti) {
      int row = wi * 64 + ti * 16 + lr;
      af[ti] = *(short8*)&xsb[row * 256 + (cb ^ ((row & 7) << 4))];
    }
    #pragma unroll
    for (int tj = 0; tj < 4; ++tj) {
      int row = wj * 64 + tj * 16 + lr;
      bf[tj] = *(short8*)&ysb[row * 256 + (cb ^ ((row & 7) << 4))];
    }
    #pragma unroll
    for (int ti = 0; ti < 4; ++ti)
      #pragma unroll
      for (int tj = 0; tj < 4; ++tj)
        acc[ti][tj] = __builtin_amdgcn_mfma_f32_16x16x32_bf16(
            af[ti], bf[tj], acc[ti][tj], 0, 0, 0);
  }

  #pragma unroll
  for (int ti = 0; ti < 4; ++ti) {
    int gi0 = I0 + wi * 64 + ti * 16;
    int l = gi0 >> 4;
    #pragma unroll
    for (int tj = 0; tj < 4; ++tj) {
      int gj = J0 + wj * 64 + tj * 16 + lr;
      int c = gj >> 3, k = gj & 7;
      int p = c + l;
      #pragma unroll
      for (int v = 0; v < 4; ++v) {
        int r = lk * 4 + v;
        float d = 1.0f - acc[ti][tj][v];
        size_t off = ((((size_t)b * PSTRIDE + p) * R_DP + r) * 64 + l) * C_DP + k;
        Dphase[off] = __float2half(exp2f(-d * L2E));
      }
    }
  }
}

// ---------------------------------------------------------------------------
// Kernel 3: producer/consumer soft-DTW DP. 16 blocks x 128 threads:
//   wave 1 (producer): pure delivery — depth-2 batches of 16 asm global
//     loads (32 KB in flight), exec-masked to the active window, written
//     into a 4-slot x 16 KB LDS ring. No compute stalls ever.
//   wave 0 (consumer): r13's verified DP body (DPP handoff, fma_mix,
//     renorm) fed by ds_read_b128 from the ring — pure compute.
// Rationale: r15 ablations show a single wave cannot overlap its VMEM and
// VALU streams (loads-only + compute-only ≈ full phase). Specialized waves
// on separate SIMDs overlap them by construction.
// Sync: volatile LDS prodCnt/consCnt; producer writes slab p, lgkmcnt(0),
// then flag (release); consumer polls flag (acquire), reads, computes,
// lgkmcnt(0), bumps consCnt. Slab p+4 written only after consCnt >= p+1.
// ---------------------------------------------------------------------------

// A = f16(lo/hi of h) * s      (fzero VGPR)
#define MIXMUL_LO(A, h, s) \
  asm("v_fma_mix_f32 %0, %1, %2, %3 op_sel_hi:[1,0,0]" : "=v"(A) : "v"(h), "v"(s), "v"(fzero))
#define MIXMUL_HI(A, h, s) \
  asm("v_fma_mix_f32 %0, %1, %2, %3 op_sel:[1,0,0] op_sel_hi:[1,0,0]" : "=v"(A) : "v"(h), "v"(s), "v"(fzero))
#define MIXFMA_LO(lf, h, a) \
  asm("v_fma_mix_f32 %0, %1, %2, %3 op_sel_hi:[1,0,0]" : "=v"(lf) : "v"(h), "v"(lf), "v"(a))
#define MIXFMA_HI(lf, h, a) \
  asm("v_fma_mix_f32 %0, %1, %2, %3 op_sel:[1,0,0] op_sel_hi:[1,0,0]" : "=v"(lf) : "v"(h), "v"(lf), "v"(a))

__device__ __forceinline__ float shup(float x, bool edge) {
  int xi = __float_as_int(x);
  int sh = __builtin_amdgcn_update_dpp(xi, xi, 0x111, 0xF, 0xF, false); // row_shr:1
  int bc = __builtin_amdgcn_update_dpp(xi, xi, 0x142, 0xF, 0xF, false); // row_bcast15
  return __int_as_float(edge ? bc : sh);
}

template<bool GUARDED>
__device__ __forceinline__ void dtw_phase_l(int c, int t, bool edge,
    const uint4 (*slot)[64], float* carry, float (&B)[9], float& O, float fzero) {
  float U[9];
  #pragma unroll
  for (int k = 0; k < 9; ++k) U[k] = shup(B[k], edge);
  float Oin = shup(O, edge);
  if (t == 0) {
    #pragma unroll
    for (int k = 0; k < 9; ++k) U[k] = 0.0f;
    if (GUARDED && c == 0) U[0] = 1.0f;   // E[0][0] = exp(-0)
    Oin = O;
  }
  bool act = GUARDED ? ((unsigned)c < 128u) : true;
  if (act) {
    if (GUARDED && c == 0) O = Oin;       // adopt neighbor's frame
    float sc = exp2f((O - Oin) * L2E);
    #pragma unroll
    for (int k = 0; k < 9; ++k) U[k] *= sc;

    #pragma unroll
    for (int r = 0; r < R_DP; ++r) {
      uint4 d = slot[r][t];               // ds_read_b128
      unsigned dw[4] = {d.x, d.y, d.z, d.w};
      float S[8], A[8];
      #pragma unroll
      for (int k = 0; k < 8; ++k) S[k] = U[k] + U[k + 1];
      #pragma unroll
      for (int q = 0; q < 4; ++q) {
        MIXMUL_LO(A[2 * q],     dw[q], S[2 * q]);
        MIXMUL_HI(A[2 * q + 1], dw[q], S[2 * q + 1]);
      }
      float oldc = carry[r], lf = oldc;
      float V[8];
      #pragma unroll
      for (int q = 0; q < 4; ++q) {
        MIXFMA_LO(lf, dw[q], A[2 * q]);     V[2 * q] = lf;
        MIXFMA_HI(lf, dw[q], A[2 * q + 1]); V[2 * q + 1] = lf;
      }
      U[0] = oldc;
      #pragma unroll
      for (int k = 1; k <= 8; ++k) U[k] = V[k - 1];
      carry[r] = lf;
    }

    // renorm: E *= 2^-ex  =>  O -= ex*ln2 ; window [-20,+12]
    float rep = carry[R_DP - 1];
    int ex = (int)((__float_as_uint(rep) >> 23) & 0xFF) - 127;
    if ((ex < -20 || ex > 12) && ex < 128) {
      float s = __uint_as_float((unsigned)(127 - ex) << 23);  // 2^-ex
      #pragma unroll
      for (int r = 0; r < R_DP; ++r) carry[r] *= s;
      #pragma unroll
      for (int k = 0; k < 9; ++k) U[k] *= s;
      O -= (float)ex * LN2;
    }
    #pragma unroll
    for (int k = 0; k < 9; ++k) B[k] = U[k];
  }
}

#define GL(Lr, SB, OFF) \
  asm volatile("global_load_dwordx4 %0, %1, %2 offset:" OFF : "=v"(Lr) : "v"(voff), "s"(SB));

#define ISSUE16(L, S0, S1, S2, S3)                               \
  GL(L[0],  S0, "0")    GL(L[1],  S0, "1024")                    \
  GL(L[2],  S0, "2048") GL(L[3],  S0, "3072")                    \
  GL(L[4],  S1, "0")    GL(L[5],  S1, "1024")                    \
  GL(L[6],  S1, "2048") GL(L[7],  S1, "3072")                    \
  GL(L[8],  S2, "0")    GL(L[9],  S2, "1024")                    \
  GL(L[10], S2, "2048") GL(L[11], S2, "3072")                    \
  GL(L[12], S3, "0")    GL(L[13], S3, "1024")                    \
  GL(L[14], S3, "2048") GL(L[15], S3, "3072")

// producer: write reg batch to ring slot (exec-masked to active lanes)
#define WRSLOT(SLOT, L)                                          \
  _Pragma("unroll")                                              \
  for (int r = 0; r < R_DP; ++r) ring[SLOT][r][t] = L[r];

__global__ __launch_bounds__(128, 1) void dtw_kernel(
    const __half* __restrict__ Dphase, float* __restrict__ out) {
  __shared__ __align__(16) uint4 ring[4][R_DP][64];   // 64 KB
  __shared__ volatile unsigned prodCnt, consCnt;

  int b = blockIdx.x;
  int tid = threadIdx.x;
  int w = __builtin_amdgcn_readfirstlane(tid >> 6);
  int t = tid & 63;
  float fzero = 0.0f;
  int voff = t * 16;

  if (tid == 0) { prodCnt = 0; consCnt = 0; }
  __syncthreads();

  const char* g = (const char*)Dphase + (size_t)b * PSTRIDE * 16384;

  if (w == 1) {
    // ----------------- PRODUCER -----------------
    uint4 A[R_DP], Bb[R_DP];
    {
      const char* s0 = g;
      const char* s1 = g + 4096;
      const char* s2 = g + 8192;
      const char* s3 = g + 12288;
      if ((unsigned)(0 - t) < 128u) { ISSUE16(A, s0, s1, s2, s3) }
    }
    for (int p = 0; p < 192; p += 2) {
      // even phase: issue slab p+1 into Bb, commit A (slab p)
      {
        int pn = (p + 1 > 190) ? 190 : p + 1;
        const char* s0 = g + ((size_t)pn << 14);
        const char* s1 = s0 + 4096;
        const char* s2 = s0 + 8192;
        const char* s3 = s0 + 12288;
        if ((unsigned)(pn - t) < 128u) { ISSUE16(Bb, s0, s1, s2, s3) }
        asm volatile("s_waitcnt vmcnt(16)" ::: "memory");
        __builtin_amdgcn_sched_barrier(0);
        while ((int)(p - (int)consCnt) >= 4) __builtin_amdgcn_s_sleep(8);
        if ((unsigned)(p - t) < 128u) { WRSLOT(p & 3, A) }
        asm volatile("s_waitcnt lgkmcnt(0)" ::: "memory");
        if (t == 0) prodCnt = p + 1;
      }
      // odd phase: issue slab p+2 into A, commit Bb (slab p+1)
      {
        int pn = (p + 2 > 190) ? 190 : p + 2;
        const char* s0 = g + ((size_t)pn << 14);
        const char* s1 = s0 + 4096;
        const char* s2 = s0 + 8192;
        const char* s3 = s0 + 12288;
        if ((unsigned)(pn - t) < 128u) { ISSUE16(A, s0, s1, s2, s3) }
        asm volatile("s_waitcnt vmcnt(16)" ::: "memory");
        __builtin_amdgcn_sched_barrier(0);
        while ((int)((p + 1) - (int)consCnt) >= 4) __builtin_amdgcn_s_sleep(8);
        if ((unsigned)((p + 1) - t) < 128u) { WRSLOT((p + 1) & 3, Bb) }
        asm volatile("s_waitcnt lgkmcnt(0)" ::: "memory");
        if (t == 0) prodCnt = p + 2;
      }
    }
    asm volatile("s_waitcnt vmcnt(0)" ::: "memory");
  } else {
    // ----------------- CONSUMER -----------------
    const bool edge = (t != 0) && ((t & 15) == 0);
    float carry[R_DP];
    #pragma unroll
    for (int r = 0; r < R_DP; ++r) carry[r] = 0.0f;
    float B[9] = {};
    float O = 0.0f;

    #define CONSUME(P, G)                                                    \
      {                                                                      \
        while ((int)prodCnt < (P) + 1) __builtin_amdgcn_s_sleep(2);          \
        asm volatile("s_waitcnt lgkmcnt(0)" ::: "memory");                   \
        __builtin_amdgcn_sched_barrier(0);                                   \
        dtw_phase_l<G>((P) - t, t, edge, ring[(P) & 3], carry, B, O, fzero); \
        asm volatile("s_waitcnt lgkmcnt(0)" ::: "memory");                   \
        if (t == 0) consCnt = (P) + 1;                                       \
      }

    for (int p = 0; p < 64; ++p)    CONSUME(p, true)
    for (int p = 64; p < 128; ++p)  CONSUME(p, false)
    for (int p = 128; p < 191; ++p) CONSUME(p, true)

    if (t == 63) out[b] = O - logf(carry[R_DP - 1]);  // R[N][M]
    #undef CONSUME
  }
}

// ---------------------------------------------------------------------------
extern "C" void kernel_launch(void* const* d_in, const int* in_sizes, int n_in,
                              void* d_out, int out_size, void* d_ws, size_t ws_size,
                              hipStream_t stream) {
  const float* x = (const float*)d_in[0];
  const float* y = (const float*)d_in[1];
  float* out = (float*)d_out;

  char* ws = (char*)d_ws;
  __half* Dphase = (__half*)ws;
  size_t dp_bytes = (size_t)BATCH * PSTRIDE * 16384;   // ~50.9 MB
  unsigned short* xnb = (unsigned short*)(ws + dp_bytes);          // 4 MB
  unsigned short* ynb = xnb + (size_t)BATCH * NROW * DFEAT;        // 4 MB

  norm_kernel<<<(2 * BATCH * NROW) / 4, 256, 0, stream>>>(x, y, xnb, ynb);
  dist_kernel<<<dim3(MCOL / 128, NROW / 128, BATCH), 256, 0, stream>>>(
      xnb, ynb, Dphase);
  dtw_kernel<<<BATCH, 128, 0, stream>>>(Dphase, out);
}